// Round 5
// baseline (364.621 us; speedup 1.0000x reference)
//
#include <hip/hip_runtime.h>
#include <math.h>

#define NBATCH 32
#define NCH 16
#define HW 65536
#define SLICES1 32   // k_sums: 2048 px/block, 2 float4 iters
#define SLICES2 32   // k_pass2: 2048 px/block, 4 float2 iters
#define TPB 256
#define NBLK2 (SLICES2 * NBATCH)   // 1024 k_pass2 blocks

// ws layout (floats) -- NO pre-zeroing required anywhere:
//  k_sums writes disjoint partial slots; k_pass2 reduces them; the completion
//  counter is reset by k_sums block (0,0,0) (kernel boundary orders it).
#define WS_PART  0                       // [t][b][slice][32]: 2*32*32*32 = 65536
#define WS_N1P   65536                   // [b][slice]: 1024
#define WS_LOSSP 66560                   // [NBLK2]: 1024
#define WS_CNT   67584                   // int completion counter
#define WS_FLOATS 67600

__device__ __forceinline__ float wave_sum(float v) {
#pragma unroll
  for (int off = 32; off > 0; off >>= 1) v += __shfl_down(v, off, 64);
  return v;
}

// grid (SLICES1, NBATCH, 2). z=0 -> S, z=1 -> T.
// Inner loop = round-3 proven body (reg loads, immediate consume, no spill).
// Output: plain stores to disjoint partial slots (replaces atomicAdd into
// memset-zeroed memory -> the memset dispatch disappears).
__global__ __launch_bounds__(TPB) void k_sums(const float* __restrict__ S,
                                              const float* __restrict__ T,
                                              const int* __restrict__ tgt,
                                              float* __restrict__ ws) {
  const int b = blockIdx.y;
  const int slice = blockIdx.x;
  const int which = blockIdx.z;  // uniform
  const int tid = threadIdx.x;
  const int lane = tid & 63, wid = tid >> 6;

  // reset k_pass2's completion counter for this iteration (any single lane;
  // k_pass2 of THIS iteration can only start after k_sums fully completes)
  if (slice == 0 && b == 0 && which == 0 && tid == 0)
    *reinterpret_cast<int*>(ws + WS_CNT) = 0;

  const float* Xb = (which ? T : S) + (size_t)b * NCH * HW;
  const int* tb = tgt + (size_t)b * HW;

  const int base = slice * (HW / SLICES1) + tid * 4;  // + it*(TPB*4)

  float acc0[NCH], acc1[NCH];
#pragma unroll
  for (int i = 0; i < NCH; ++i) { acc0[i] = 0.f; acc1[i] = 0.f; }
  float n1 = 0.f;

  for (int it = 0; it < 2; ++it) {
    const int p = base + it * (TPB * 4);
    const int4 tv = *(const int4*)(tb + p);
    float4 x[NCH];
#pragma unroll
    for (int i = 0; i < NCH; ++i)
      x[i] = *(const float4*)(Xb + (size_t)i * HW + p);

    const float m0 = (tv.x == 1) ? 1.f : 0.f;
    const float m1 = (tv.y == 1) ? 1.f : 0.f;
    const float m2 = (tv.z == 1) ? 1.f : 0.f;
    const float m3 = (tv.w == 1) ? 1.f : 0.f;
    n1 += (m0 + m1) + (m2 + m3);

    float s0a = 0.f, s0b = 0.f, s1a = 0.f, s1b = 0.f;
    float s2a = 0.f, s2b = 0.f, s3a = 0.f, s3b = 0.f;
#pragma unroll
    for (int i = 0; i < NCH; i += 2) {
      s0a = fmaf(x[i].x, x[i].x, s0a);   s0b = fmaf(x[i + 1].x, x[i + 1].x, s0b);
      s1a = fmaf(x[i].y, x[i].y, s1a);   s1b = fmaf(x[i + 1].y, x[i + 1].y, s1b);
      s2a = fmaf(x[i].z, x[i].z, s2a);   s2b = fmaf(x[i + 1].z, x[i + 1].z, s2b);
      s3a = fmaf(x[i].w, x[i].w, s3a);   s3b = fmaf(x[i + 1].w, x[i + 1].w, s3b);
    }
    const float i0 = 1.f / fmaxf(sqrtf(s0a + s0b), 1e-12f);
    const float i1 = 1.f / fmaxf(sqrtf(s1a + s1b), 1e-12f);
    const float i2 = 1.f / fmaxf(sqrtf(s2a + s2b), 1e-12f);
    const float i3 = 1.f / fmaxf(sqrtf(s3a + s3b), 1e-12f);

#pragma unroll
    for (int i = 0; i < NCH; ++i) {
      const float f0 = x[i].x * i0, f1 = x[i].y * i1;
      const float f2 = x[i].z * i2, f3 = x[i].w * i3;
      const float t_ = (f0 + f1) + (f2 + f3);
      const float m_ = fmaf(f0, m0, fmaf(f1, m1, fmaf(f2, m2, f3 * m3)));
      acc1[i] += m_;
      acc0[i] += t_ - m_;
    }
  }

  // ---- LDS-transpose reduction (proven conflict-free, round 3) ----
  __shared__ float lds[32][TPB + 1];
  __shared__ float redn[4];
#pragma unroll
  for (int i = 0; i < NCH; ++i) {
    lds[i][tid] = acc0[i];
    lds[16 + i][tid] = acc1[i];
  }
  n1 = wave_sum(n1);
  if (lane == 0) redn[wid] = n1;
  __syncthreads();

  const int row = tid >> 3, seg = tid & 7;  // 32 rows x 8 segments
  float s = 0.f;
#pragma unroll
  for (int k0 = 0; k0 < 32; ++k0) {
    const int k = (k0 + seg * 4) & 31;  // bank-swizzle: conflict-free
    s += lds[row][seg * 32 + k];
  }
  s += __shfl_down(s, 4, 8);
  s += __shfl_down(s, 2, 8);
  s += __shfl_down(s, 1, 8);

  float* part = ws + WS_PART + (((size_t)which * NBATCH + b) * SLICES1 + slice) * 32;
  if (seg == 0) part[row] = s;   // disjoint slot: no atomic, no pre-zero
  if (tid == 0 && which == 0)
    ws[WS_N1P + b * SLICES1 + slice] = redn[0] + redn[1] + redn[2] + redn[3];
}

// per-pixel pcsim given ss, raw dots vs class means, target, mean norms
__device__ __forceinline__ float pc_one(float ss, float d0, float d1, int t,
                                        float nm0, float nm1) {
  const float n = sqrtf(ss);
  const float inv = 1.f / fmaxf(n, 1e-12f);
  const float na = n * inv;  // == |feat| after normalize
  const float c0 = (d0 * inv) / fmaxf(na * nm0, 1e-8f);
  const float c1 = (d1 * inv) / fmaxf(na * nm1, 1e-8f);
  return expf((t == 1) ? (c1 - c0) : (c0 - c1));
}

// grid (SLICES2, NBATCH). Preamble reduces k_sums partials in parallel; tail
// uses the last-block pattern to fold the former k_final into this kernel.
__global__ __launch_bounds__(TPB) void k_pass2(const float* __restrict__ S,
                                               const float* __restrict__ T,
                                               const int* __restrict__ tgt,
                                               float* __restrict__ ws,
                                               float* __restrict__ out) {
  __shared__ __align__(16) float sm[72];  // [0..63] means, [64..67] mean norms
  __shared__ float ldp[4][64];
  __shared__ float ldn[32];
  __shared__ float red4[4];
  __shared__ int isLast;
  const int b = blockIdx.y;
  const int slice = blockIdx.x;
  const int tid = threadIdx.x;

  // ---- reduce partials: thread (q, c64) sums 8 slices (independent loads) ----
  {
    const int c64 = tid & 63, q = tid >> 6;
    const int t_ = c64 >> 5, c32 = c64 & 31;
    const float* pp = ws + WS_PART + (((size_t)t_ * NBATCH + b) * SLICES1) * 32 + c32;
    float s8 = 0.f;
#pragma unroll
    for (int k = 0; k < 8; ++k) s8 += pp[(q * 8 + k) * 32];
    ldp[q][c64] = s8;
  }
  if (tid < 32) ldn[tid] = ws[WS_N1P + b * SLICES1 + tid];
  __syncthreads();

  if (tid < 64) {
    float n1 = 0.f;
#pragma unroll
    for (int k = 0; k < 32; ++k) n1 += ldn[k];
    const int cls = (tid >> 4) & 1;
    const float cnt = (cls ? n1 : ((float)HW - n1)) + 1e-6f;
    sm[tid] = (ldp[0][tid] + ldp[1][tid] + ldp[2][tid] + ldp[3][tid]) / cnt;
  }
  __syncthreads();
  if (tid < 4) {  // tid = t*2+cls
    float ss = 0.f;
    const int base_ = (tid >> 1) * 32 + (tid & 1) * 16;
#pragma unroll
    for (int c = 0; c < NCH; ++c) { const float v = sm[base_ + c]; ss = fmaf(v, v, ss); }
    sm[64 + tid] = sqrtf(ss);
  }
  __syncthreads();

  const int base = slice * (HW / SLICES2) + tid * 2;  // + it*(TPB*2)
  const float* Sb = S + (size_t)b * NCH * HW;
  const float* Tb = T + (size_t)b * NCH * HW;
  const int* tb = tgt + (size_t)b * HW;

  const float nmS0 = sm[64], nmS1 = sm[65], nmT0 = sm[66], nmT1 = sm[67];
  float lacc = 0.f;

  for (int it = 0; it < 4; ++it) {
    const int p = base + it * (TPB * 2);
    const int2 tv = *(const int2*)(tb + p);
    float2 xs[NCH], xt[NCH];
#pragma unroll
    for (int i = 0; i < NCH; ++i)
      xs[i] = *(const float2*)(Sb + (size_t)i * HW + p);
#pragma unroll
    for (int i = 0; i < NCH; ++i)
      xt[i] = *(const float2*)(Tb + (size_t)i * HW + p);

    // ---- S (T loads still in flight) ----
    float ss0 = 0.f, ss1 = 0.f, d00 = 0.f, d01 = 0.f, d10 = 0.f, d11 = 0.f;
#pragma unroll
    for (int i = 0; i < NCH; ++i) {
      const float w0 = sm[i], w1 = sm[16 + i];  // wave-uniform -> broadcast
      ss0 = fmaf(xs[i].x, xs[i].x, ss0); ss1 = fmaf(xs[i].y, xs[i].y, ss1);
      d00 = fmaf(xs[i].x, w0, d00);      d01 = fmaf(xs[i].y, w0, d01);
      d10 = fmaf(xs[i].x, w1, d10);      d11 = fmaf(xs[i].y, w1, d11);
    }
    const float pcS0 = pc_one(ss0, d00, d10, tv.x, nmS0, nmS1);
    const float pcS1 = pc_one(ss1, d01, d11, tv.y, nmS0, nmS1);

    // ---- T ----
    ss0 = 0.f; ss1 = 0.f; d00 = 0.f; d01 = 0.f; d10 = 0.f; d11 = 0.f;
#pragma unroll
    for (int i = 0; i < NCH; ++i) {
      const float w0 = sm[32 + i], w1 = sm[48 + i];
      ss0 = fmaf(xt[i].x, xt[i].x, ss0); ss1 = fmaf(xt[i].y, xt[i].y, ss1);
      d00 = fmaf(xt[i].x, w0, d00);      d01 = fmaf(xt[i].y, w0, d01);
      d10 = fmaf(xt[i].x, w1, d10);      d11 = fmaf(xt[i].y, w1, d11);
    }
    const float pcT0 = pc_one(ss0, d00, d10, tv.x, nmT0, nmT1);
    const float pcT1 = pc_one(ss1, d01, d11, tv.y, nmT0, nmT1);

    const float e0 = pcS0 - pcT0, e1 = pcS1 - pcT1;
    lacc += e0 * e0 + e1 * e1;
  }

  lacc = wave_sum(lacc);
  if ((tid & 63) == 0) red4[tid >> 6] = lacc;
  __syncthreads();

  const int bidx = b * SLICES2 + slice;
  if (tid == 0) {
    ws[WS_LOSSP + bidx] = red4[0] + red4[1] + red4[2] + red4[3];
    __threadfence();  // release: partial visible before the counter bump
    const int old = atomicAdd(reinterpret_cast<int*>(ws + WS_CNT), 1);
    isLast = (old == NBLK2 - 1);
  }
  __syncthreads();

  if (isLast) {            // exactly one block: fold the former k_final here
    __threadfence();       // acquire: see all other blocks' partials
    if (tid < 64) {
      float s = 0.f;
#pragma unroll
      for (int k = 0; k < NBLK2 / 64; ++k) s += ws[WS_LOSSP + tid + 64 * k];
      s = wave_sum(s);
      if (tid == 0) out[0] = s * (1.f / 2097152.f);  // N = 2^21, exact
    }
  }
}

extern "C" void kernel_launch(void* const* d_in, const int* in_sizes, int n_in,
                              void* d_out, int out_size, void* d_ws, size_t ws_size,
                              hipStream_t stream) {
  const float* S = (const float*)d_in[0];
  const float* T = (const float*)d_in[1];
  const int* tgt = (const int*)d_in[2];
  float* ws = (float*)d_ws;
  float* out = (float*)d_out;

  // 2 dispatches total: no memset (disjoint partials), no k_final (last-block)
  dim3 g1(SLICES1, NBATCH, 2);
  k_sums<<<g1, TPB, 0, stream>>>(S, T, tgt, ws);
  dim3 g2(SLICES2, NBATCH);
  k_pass2<<<g2, TPB, 0, stream>>>(S, T, tgt, ws, out);
}

// Round 6
// 316.226 us; speedup vs baseline: 1.1530x; 1.1530x over previous
//
#include <hip/hip_runtime.h>
#include <math.h>

#define NBATCH 32
#define NCH 16
#define HW 65536
#define SLICES1 32   // k_sums: 2048 px/block, 2 float4 iters
#define SLICES2 32   // k_pass2: 2048 px/block
#define TPB 256

// control region (floats), relative to 'ctrl' pointer (NO pre-zero needed;
// all slots are written with plain disjoint stores)
#define CT_PART  0       // [t][b][slice][32] : 2*32*32*32 = 65536
#define CT_N1P   65536   // [b][slice] : 1024
#define CT_LOSSP 66560   // [b*SLICES2+slice] : 1024
#define CT_FLOATS 67584

// fp16 normalized-feature cache: [t][b][ch][px] halves
#define CACHE_HALFS ((size_t)2 * NBATCH * NCH * HW)          // 67,108,864
#define CACHE_BYTES (CACHE_HALFS * 2)                        // 128 MB

typedef float f4 __attribute__((ext_vector_type(4)));
typedef _Float16 h4 __attribute__((ext_vector_type(4)));

__device__ __forceinline__ float wave_sum(float v) {
#pragma unroll
  for (int off = 32; off > 0; off >>= 1) v += __shfl_down(v, off, 64);
  return v;
}

// grid (SLICES1, NBATCH, 2). z=0 -> S, z=1 -> T.
// THEORY: consumption is capped at ~2.8 TB/s by the XCD<->fabric READ path
// (warm-L3 == cold-HBM == shape-independent across 6 structural variants).
// Only byte reduction helps. This kernel additionally WRITES the normalized
// features as fp16 (opposite fabric direction ~ free) so pass 2 reads half
// the bytes and skips the norm recompute.
template <bool CACHE>
__global__ __launch_bounds__(TPB) void k_sums(const float* __restrict__ S,
                                              const float* __restrict__ T,
                                              const int* __restrict__ tgt,
                                              float* __restrict__ ctrl,
                                              _Float16* __restrict__ cache) {
  const int b = blockIdx.y;
  const int slice = blockIdx.x;
  const int which = blockIdx.z;  // uniform
  const int tid = threadIdx.x;
  const int lane = tid & 63, wid = tid >> 6;

  const float* Xb = (which ? T : S) + (size_t)b * NCH * HW;
  const int* tb = tgt + (size_t)b * HW;
  _Float16* cb = cache + ((size_t)(which * NBATCH + b)) * NCH * HW;

  const int base = slice * (HW / SLICES1) + tid * 4;  // + it*(TPB*4)

  float acc0[NCH], acc1[NCH];
#pragma unroll
  for (int i = 0; i < NCH; ++i) { acc0[i] = 0.f; acc1[i] = 0.f; }
  float n1 = 0.f;

  for (int it = 0; it < 2; ++it) {
    const int p = base + it * (TPB * 4);
    const int4 tv = *(const int4*)(tb + p);
    f4 x[NCH];
#pragma unroll
    for (int i = 0; i < NCH; ++i)
      x[i] = __builtin_nontemporal_load((const f4*)(Xb + (size_t)i * HW + p));

    const float m0 = (tv.x == 1) ? 1.f : 0.f;
    const float m1 = (tv.y == 1) ? 1.f : 0.f;
    const float m2 = (tv.z == 1) ? 1.f : 0.f;
    const float m3 = (tv.w == 1) ? 1.f : 0.f;
    n1 += (m0 + m1) + (m2 + m3);

    float s0a = 0.f, s0b = 0.f, s1a = 0.f, s1b = 0.f;
    float s2a = 0.f, s2b = 0.f, s3a = 0.f, s3b = 0.f;
#pragma unroll
    for (int i = 0; i < NCH; i += 2) {
      s0a = fmaf(x[i].x, x[i].x, s0a);   s0b = fmaf(x[i + 1].x, x[i + 1].x, s0b);
      s1a = fmaf(x[i].y, x[i].y, s1a);   s1b = fmaf(x[i + 1].y, x[i + 1].y, s1b);
      s2a = fmaf(x[i].z, x[i].z, s2a);   s2b = fmaf(x[i + 1].z, x[i + 1].z, s2b);
      s3a = fmaf(x[i].w, x[i].w, s3a);   s3b = fmaf(x[i + 1].w, x[i + 1].w, s3b);
    }
    const float i0 = 1.f / fmaxf(sqrtf(s0a + s0b), 1e-12f);
    const float i1 = 1.f / fmaxf(sqrtf(s1a + s1b), 1e-12f);
    const float i2 = 1.f / fmaxf(sqrtf(s2a + s2b), 1e-12f);
    const float i3 = 1.f / fmaxf(sqrtf(s3a + s3b), 1e-12f);

#pragma unroll
    for (int i = 0; i < NCH; ++i) {
      const float f0 = x[i].x * i0, f1 = x[i].y * i1;
      const float f2 = x[i].z * i2, f3 = x[i].w * i3;
      if constexpr (CACHE) {
        h4 q;
        q.x = (_Float16)f0; q.y = (_Float16)f1;
        q.z = (_Float16)f2; q.w = (_Float16)f3;
        __builtin_nontemporal_store(q, (h4*)(cb + (size_t)i * HW + p));
      }
      const float t_ = (f0 + f1) + (f2 + f3);
      const float m_ = fmaf(f0, m0, fmaf(f1, m1, fmaf(f2, m2, f3 * m3)));
      acc1[i] += m_;
      acc0[i] += t_ - m_;
    }
  }

  // ---- LDS-transpose reduction (proven conflict-free, rounds 3-5) ----
  __shared__ float lds[32][TPB + 1];
  __shared__ float redn[4];
#pragma unroll
  for (int i = 0; i < NCH; ++i) {
    lds[i][tid] = acc0[i];
    lds[16 + i][tid] = acc1[i];
  }
  n1 = wave_sum(n1);
  if (lane == 0) redn[wid] = n1;
  __syncthreads();

  const int row = tid >> 3, seg = tid & 7;  // 32 rows x 8 segments
  float s = 0.f;
#pragma unroll
  for (int k0 = 0; k0 < 32; ++k0) {
    const int k = (k0 + seg * 4) & 31;
    s += lds[row][seg * 32 + k];
  }
  s += __shfl_down(s, 4, 8);
  s += __shfl_down(s, 2, 8);
  s += __shfl_down(s, 1, 8);

  float* part = ctrl + CT_PART + (((size_t)which * NBATCH + b) * SLICES1 + slice) * 32;
  if (seg == 0) part[row] = s;   // disjoint slot: no atomic, no pre-zero
  if (tid == 0 && which == 0)
    ctrl[CT_N1P + b * SLICES1 + slice] = redn[0] + redn[1] + redn[2] + redn[3];
}

// fallback-path pcsim (raw x): matches reference semantics exactly
__device__ __forceinline__ float pc_one(float ss, float d0, float d1, int t,
                                        float nm0, float nm1) {
  const float n = sqrtf(ss);
  const float inv = 1.f / fmaxf(n, 1e-12f);
  const float na = n * inv;
  const float c0 = (d0 * inv) / fmaxf(na * nm0, 1e-8f);
  const float c1 = (d1 * inv) / fmaxf(na * nm1, 1e-8f);
  return expf((t == 1) ? (c1 - c0) : (c0 - c1));
}

// grid (SLICES2, NBATCH). CACHE=true: read fp16 normalized features (136 MB
// instead of 272 MB on the bottleneck read direction); na==1 so no ss/sqrt.
template <bool CACHE>
__global__ __launch_bounds__(TPB) void k_pass2(const float* __restrict__ S,
                                               const float* __restrict__ T,
                                               const int* __restrict__ tgt,
                                               float* __restrict__ ctrl,
                                               const _Float16* __restrict__ cache) {
  __shared__ __align__(16) float sm[72];  // [0..63] means, [64..67] mean norms
  __shared__ float ldp[4][64];
  __shared__ float ldn[32];
  __shared__ float red4[4];
  const int b = blockIdx.y;
  const int slice = blockIdx.x;
  const int tid = threadIdx.x;

  // ---- reduce k_sums partials in parallel (8 independent loads/thread) ----
  {
    const int c64 = tid & 63, q = tid >> 6;
    const int t_ = c64 >> 5, c32 = c64 & 31;
    const float* pp = ctrl + CT_PART + (((size_t)t_ * NBATCH + b) * SLICES1) * 32 + c32;
    float s8 = 0.f;
#pragma unroll
    for (int k = 0; k < 8; ++k) s8 += pp[(q * 8 + k) * 32];
    ldp[q][c64] = s8;
  }
  if (tid < 32) ldn[tid] = ctrl[CT_N1P + b * SLICES1 + tid];
  __syncthreads();

  if (tid < 64) {
    float n1 = 0.f;
#pragma unroll
    for (int k = 0; k < 32; ++k) n1 += ldn[k];
    const int cls = (tid >> 4) & 1;
    const float cnt = (cls ? n1 : ((float)HW - n1)) + 1e-6f;
    sm[tid] = (ldp[0][tid] + ldp[1][tid] + ldp[2][tid] + ldp[3][tid]) / cnt;
  }
  __syncthreads();
  if (tid < 4) {  // tid = t*2+cls
    float ss = 0.f;
    const int base_ = (tid >> 1) * 32 + (tid & 1) * 16;
#pragma unroll
    for (int c = 0; c < NCH; ++c) { const float v = sm[base_ + c]; ss = fmaf(v, v, ss); }
    sm[64 + tid] = sqrtf(ss);
  }
  __syncthreads();

  const int* tb = tgt + (size_t)b * HW;
  float lacc = 0.f;

  if constexpr (CACHE) {
    const _Float16* cS = cache + (size_t)b * NCH * HW;
    const _Float16* cT = cache + ((size_t)(NBATCH + b)) * NCH * HW;
    const float rS0 = 1.f / fmaxf(sm[64], 1e-8f);
    const float rS1 = 1.f / fmaxf(sm[65], 1e-8f);
    const float rT0 = 1.f / fmaxf(sm[66], 1e-8f);
    const float rT1 = 1.f / fmaxf(sm[67], 1e-8f);
    const int base = slice * (HW / SLICES2) + tid * 4;  // + it*(TPB*4)

    for (int it = 0; it < 2; ++it) {
      const int p = base + it * (TPB * 4);
      const int4 tv = *(const int4*)(tb + p);
      h4 xs[NCH], xt[NCH];
#pragma unroll
      for (int i = 0; i < NCH; ++i)
        xs[i] = __builtin_nontemporal_load((const h4*)(cS + (size_t)i * HW + p));
#pragma unroll
      for (int i = 0; i < NCH; ++i)
        xt[i] = __builtin_nontemporal_load((const h4*)(cT + (size_t)i * HW + p));

      // ---- S (T loads in flight) ----
      f4 a0 = {0, 0, 0, 0}, a1 = {0, 0, 0, 0};
#pragma unroll
      for (int i = 0; i < NCH; ++i) {
        const float w0 = sm[i], w1 = sm[16 + i];
        const float x0 = (float)xs[i].x, x1 = (float)xs[i].y;
        const float x2 = (float)xs[i].z, x3 = (float)xs[i].w;
        a0.x = fmaf(x0, w0, a0.x); a0.y = fmaf(x1, w0, a0.y);
        a0.z = fmaf(x2, w0, a0.z); a0.w = fmaf(x3, w0, a0.w);
        a1.x = fmaf(x0, w1, a1.x); a1.y = fmaf(x1, w1, a1.y);
        a1.z = fmaf(x2, w1, a1.z); a1.w = fmaf(x3, w1, a1.w);
      }
      const float pcS0 = expf((tv.x == 1) ? a1.x * rS1 - a0.x * rS0 : a0.x * rS0 - a1.x * rS1);
      const float pcS1 = expf((tv.y == 1) ? a1.y * rS1 - a0.y * rS0 : a0.y * rS0 - a1.y * rS1);
      const float pcS2 = expf((tv.z == 1) ? a1.z * rS1 - a0.z * rS0 : a0.z * rS0 - a1.z * rS1);
      const float pcS3 = expf((tv.w == 1) ? a1.w * rS1 - a0.w * rS0 : a0.w * rS0 - a1.w * rS1);

      // ---- T ----
      a0 = {0, 0, 0, 0}; a1 = {0, 0, 0, 0};
#pragma unroll
      for (int i = 0; i < NCH; ++i) {
        const float w0 = sm[32 + i], w1 = sm[48 + i];
        const float x0 = (float)xt[i].x, x1 = (float)xt[i].y;
        const float x2 = (float)xt[i].z, x3 = (float)xt[i].w;
        a0.x = fmaf(x0, w0, a0.x); a0.y = fmaf(x1, w0, a0.y);
        a0.z = fmaf(x2, w0, a0.z); a0.w = fmaf(x3, w0, a0.w);
        a1.x = fmaf(x0, w1, a1.x); a1.y = fmaf(x1, w1, a1.y);
        a1.z = fmaf(x2, w1, a1.z); a1.w = fmaf(x3, w1, a1.w);
      }
      const float pcT0 = expf((tv.x == 1) ? a1.x * rT1 - a0.x * rT0 : a0.x * rT0 - a1.x * rT1);
      const float pcT1 = expf((tv.y == 1) ? a1.y * rT1 - a0.y * rT0 : a0.y * rT0 - a1.y * rT1);
      const float pcT2 = expf((tv.z == 1) ? a1.z * rT1 - a0.z * rT0 : a0.z * rT0 - a1.z * rT1);
      const float pcT3 = expf((tv.w == 1) ? a1.w * rT1 - a0.w * rT0 : a0.w * rT0 - a1.w * rT1);

      const float e0 = pcS0 - pcT0, e1 = pcS1 - pcT1;
      const float e2 = pcS2 - pcT2, e3 = pcS3 - pcT3;
      lacc += (e0 * e0 + e1 * e1) + (e2 * e2 + e3 * e3);
    }
  } else {
    const float* Sb = S + (size_t)b * NCH * HW;
    const float* Tb = T + (size_t)b * NCH * HW;
    const float nmS0 = sm[64], nmS1 = sm[65], nmT0 = sm[66], nmT1 = sm[67];
    const int base = slice * (HW / SLICES2) + tid * 2;  // + it*(TPB*2)

    for (int it = 0; it < 4; ++it) {
      const int p = base + it * (TPB * 2);
      const int2 tv = *(const int2*)(tb + p);
      float2 xs[NCH], xt[NCH];
#pragma unroll
      for (int i = 0; i < NCH; ++i) xs[i] = *(const float2*)(Sb + (size_t)i * HW + p);
#pragma unroll
      for (int i = 0; i < NCH; ++i) xt[i] = *(const float2*)(Tb + (size_t)i * HW + p);

      float ss0 = 0.f, ss1 = 0.f, d00 = 0.f, d01 = 0.f, d10 = 0.f, d11 = 0.f;
#pragma unroll
      for (int i = 0; i < NCH; ++i) {
        const float w0 = sm[i], w1 = sm[16 + i];
        ss0 = fmaf(xs[i].x, xs[i].x, ss0); ss1 = fmaf(xs[i].y, xs[i].y, ss1);
        d00 = fmaf(xs[i].x, w0, d00);      d01 = fmaf(xs[i].y, w0, d01);
        d10 = fmaf(xs[i].x, w1, d10);      d11 = fmaf(xs[i].y, w1, d11);
      }
      const float pcS0 = pc_one(ss0, d00, d10, tv.x, nmS0, nmS1);
      const float pcS1 = pc_one(ss1, d01, d11, tv.y, nmS0, nmS1);

      ss0 = 0.f; ss1 = 0.f; d00 = 0.f; d01 = 0.f; d10 = 0.f; d11 = 0.f;
#pragma unroll
      for (int i = 0; i < NCH; ++i) {
        const float w0 = sm[32 + i], w1 = sm[48 + i];
        ss0 = fmaf(xt[i].x, xt[i].x, ss0); ss1 = fmaf(xt[i].y, xt[i].y, ss1);
        d00 = fmaf(xt[i].x, w0, d00);      d01 = fmaf(xt[i].y, w0, d01);
        d10 = fmaf(xt[i].x, w1, d10);      d11 = fmaf(xt[i].y, w1, d11);
      }
      const float pcT0 = pc_one(ss0, d00, d10, tv.x, nmT0, nmT1);
      const float pcT1 = pc_one(ss1, d01, d11, tv.y, nmT0, nmT1);

      const float e0 = pcS0 - pcT0, e1 = pcS1 - pcT1;
      lacc += e0 * e0 + e1 * e1;
    }
  }

  lacc = wave_sum(lacc);
  if ((tid & 63) == 0) red4[tid >> 6] = lacc;
  __syncthreads();
  if (tid == 0)
    ctrl[CT_LOSSP + b * SLICES2 + slice] = red4[0] + red4[1] + red4[2] + red4[3];
}

// one block: reduce the 1024 disjoint loss partials (no atomics anywhere)
__global__ void k_final(const float* __restrict__ ctrl, float* __restrict__ out) {
  __shared__ float r4[4];
  const int tid = threadIdx.x;
  float s = ctrl[CT_LOSSP + tid] + ctrl[CT_LOSSP + tid + 256] +
            ctrl[CT_LOSSP + tid + 512] + ctrl[CT_LOSSP + tid + 768];
  s = wave_sum(s);
  if ((tid & 63) == 0) r4[tid >> 6] = s;
  __syncthreads();
  if (tid == 0)
    out[0] = (r4[0] + r4[1] + r4[2] + r4[3]) * (1.f / 2097152.f);  // N = 2^21
}

extern "C" void kernel_launch(void* const* d_in, const int* in_sizes, int n_in,
                              void* d_out, int out_size, void* d_ws, size_t ws_size,
                              hipStream_t stream) {
  const float* S = (const float*)d_in[0];
  const float* T = (const float*)d_in[1];
  const int* tgt = (const int*)d_in[2];
  float* out = (float*)d_out;

  const size_t need = CACHE_BYTES + (size_t)CT_FLOATS * 4;
  const bool cached = ws_size >= need;
  _Float16* cache = (_Float16*)d_ws;
  float* ctrl = cached ? (float*)((char*)d_ws + CACHE_BYTES) : (float*)d_ws;

  dim3 g1(SLICES1, NBATCH, 2);
  dim3 g2(SLICES2, NBATCH);
  if (cached) {
    k_sums<true><<<g1, TPB, 0, stream>>>(S, T, tgt, ctrl, cache);
    k_pass2<true><<<g2, TPB, 0, stream>>>(S, T, tgt, ctrl, cache);
  } else {
    k_sums<false><<<g1, TPB, 0, stream>>>(S, T, tgt, ctrl, cache);
    k_pass2<false><<<g2, TPB, 0, stream>>>(S, T, tgt, ctrl, cache);
  }
  k_final<<<1, 256, 0, stream>>>(ctrl, out);
}

// Round 7
// 312.844 us; speedup vs baseline: 1.1655x; 1.0108x over previous
//
#include <hip/hip_runtime.h>
#include <math.h>

#define NBATCH 32
#define NCH 16
#define HW 65536
#define SLICES1 32   // k_sums: 2048 px/block, 2 float4 iters
#define SLICES2 32   // k_pass2: 2048 px/block, 8 px/thread one-shot
#define TPB 256

// control region (floats), relative to 'ctrl' pointer (NO pre-zero needed;
// all slots are written with plain disjoint stores)
#define CT_PART  0       // [t][b][slice][32] : 2*32*32*32 = 65536
#define CT_N1P   65536   // [b][slice] : 1024
#define CT_LOSSP 66560   // [b*SLICES2+slice] : 1024
#define CT_FLOATS 67584

// fp16 normalized-feature cache: [t][b][ch][px] halves
#define CACHE_HALFS ((size_t)2 * NBATCH * NCH * HW)          // 67,108,864
#define CACHE_BYTES (CACHE_HALFS * 2)                        // 128 MB

typedef float f4 __attribute__((ext_vector_type(4)));
typedef _Float16 h4 __attribute__((ext_vector_type(4)));
typedef _Float16 h8 __attribute__((ext_vector_type(8)));

__device__ __forceinline__ float wave_sum(float v) {
#pragma unroll
  for (int off = 32; off > 0; off >>= 1) v += __shfl_down(v, off, 64);
  return v;
}

// grid (SLICES1, NBATCH, 2). z=0 -> S, z=1 -> T.
// Proven round-6 body (82 us, 4.93 TB/s combined rw): NT fp32 reads, fp16
// normalized-feature NT writes (pass 2 then reads half the bytes).
template <bool CACHE>
__global__ __launch_bounds__(TPB) void k_sums(const float* __restrict__ S,
                                              const float* __restrict__ T,
                                              const int* __restrict__ tgt,
                                              float* __restrict__ ctrl,
                                              _Float16* __restrict__ cache) {
  const int b = blockIdx.y;
  const int slice = blockIdx.x;
  const int which = blockIdx.z;  // uniform
  const int tid = threadIdx.x;
  const int lane = tid & 63, wid = tid >> 6;

  const float* Xb = (which ? T : S) + (size_t)b * NCH * HW;
  const int* tb = tgt + (size_t)b * HW;
  _Float16* cb = cache + ((size_t)(which * NBATCH + b)) * NCH * HW;

  const int base = slice * (HW / SLICES1) + tid * 4;  // + it*(TPB*4)

  float acc0[NCH], acc1[NCH];
#pragma unroll
  for (int i = 0; i < NCH; ++i) { acc0[i] = 0.f; acc1[i] = 0.f; }
  float n1 = 0.f;

  for (int it = 0; it < 2; ++it) {
    const int p = base + it * (TPB * 4);
    const int4 tv = *(const int4*)(tb + p);
    f4 x[NCH];
#pragma unroll
    for (int i = 0; i < NCH; ++i)
      x[i] = __builtin_nontemporal_load((const f4*)(Xb + (size_t)i * HW + p));

    const float m0 = (tv.x == 1) ? 1.f : 0.f;
    const float m1 = (tv.y == 1) ? 1.f : 0.f;
    const float m2 = (tv.z == 1) ? 1.f : 0.f;
    const float m3 = (tv.w == 1) ? 1.f : 0.f;
    n1 += (m0 + m1) + (m2 + m3);

    float s0a = 0.f, s0b = 0.f, s1a = 0.f, s1b = 0.f;
    float s2a = 0.f, s2b = 0.f, s3a = 0.f, s3b = 0.f;
#pragma unroll
    for (int i = 0; i < NCH; i += 2) {
      s0a = fmaf(x[i].x, x[i].x, s0a);   s0b = fmaf(x[i + 1].x, x[i + 1].x, s0b);
      s1a = fmaf(x[i].y, x[i].y, s1a);   s1b = fmaf(x[i + 1].y, x[i + 1].y, s1b);
      s2a = fmaf(x[i].z, x[i].z, s2a);   s2b = fmaf(x[i + 1].z, x[i + 1].z, s2b);
      s3a = fmaf(x[i].w, x[i].w, s3a);   s3b = fmaf(x[i + 1].w, x[i + 1].w, s3b);
    }
    const float i0 = 1.f / fmaxf(sqrtf(s0a + s0b), 1e-12f);
    const float i1 = 1.f / fmaxf(sqrtf(s1a + s1b), 1e-12f);
    const float i2 = 1.f / fmaxf(sqrtf(s2a + s2b), 1e-12f);
    const float i3 = 1.f / fmaxf(sqrtf(s3a + s3b), 1e-12f);

#pragma unroll
    for (int i = 0; i < NCH; ++i) {
      const float f0 = x[i].x * i0, f1 = x[i].y * i1;
      const float f2 = x[i].z * i2, f3 = x[i].w * i3;
      if constexpr (CACHE) {
        h4 q;
        q.x = (_Float16)f0; q.y = (_Float16)f1;
        q.z = (_Float16)f2; q.w = (_Float16)f3;
        __builtin_nontemporal_store(q, (h4*)(cb + (size_t)i * HW + p));
      }
      const float t_ = (f0 + f1) + (f2 + f3);
      const float m_ = fmaf(f0, m0, fmaf(f1, m1, fmaf(f2, m2, f3 * m3)));
      acc1[i] += m_;
      acc0[i] += t_ - m_;
    }
  }

  // ---- LDS-transpose reduction (proven conflict-free, rounds 3-6) ----
  __shared__ float lds[32][TPB + 1];
  __shared__ float redn[4];
#pragma unroll
  for (int i = 0; i < NCH; ++i) {
    lds[i][tid] = acc0[i];
    lds[16 + i][tid] = acc1[i];
  }
  n1 = wave_sum(n1);
  if (lane == 0) redn[wid] = n1;
  __syncthreads();

  const int row = tid >> 3, seg = tid & 7;  // 32 rows x 8 segments
  float s = 0.f;
#pragma unroll
  for (int k0 = 0; k0 < 32; ++k0) {
    const int k = (k0 + seg * 4) & 31;
    s += lds[row][seg * 32 + k];
  }
  s += __shfl_down(s, 4, 8);
  s += __shfl_down(s, 2, 8);
  s += __shfl_down(s, 1, 8);

  float* part = ctrl + CT_PART + (((size_t)which * NBATCH + b) * SLICES1 + slice) * 32;
  if (seg == 0) part[row] = s;   // disjoint slot: no atomic, no pre-zero
  if (tid == 0 && which == 0)
    ctrl[CT_N1P + b * SLICES1 + slice] = redn[0] + redn[1] + redn[2] + redn[3];
}

// fallback-path pcsim (raw x): matches reference semantics exactly
__device__ __forceinline__ float pc_one(float ss, float d0, float d1, int t,
                                        float nm0, float nm1) {
  const float n = sqrtf(ss);
  const float inv = 1.f / fmaxf(n, 1e-12f);
  const float na = n * inv;
  const float c0 = (d0 * inv) / fmaxf(na * nm0, 1e-8f);
  const float c1 = (d1 * inv) / fmaxf(na * nm1, 1e-8f);
  return expf((t == 1) ? (c1 - c0) : (c0 - c1));
}

// grid (SLICES2, NBATCH). CACHE=true: 8 px/thread ONE-SHOT burst of 16B NT
// loads (32x h8 + 2x int4) -- previous round used 8B h4 loads in a 2-iter
// loop and ran at only ~1.8 TB/s; this matches k_sums' 16B-load shape.
template <bool CACHE>
__global__ __launch_bounds__(TPB) void k_pass2(const float* __restrict__ S,
                                               const float* __restrict__ T,
                                               const int* __restrict__ tgt,
                                               float* __restrict__ ctrl,
                                               const _Float16* __restrict__ cache) {
  __shared__ __align__(16) float sm[72];  // [0..63] means, [64..67] mean norms
  __shared__ float ldp[4][64];
  __shared__ float ldn[32];
  __shared__ float red4[4];
  const int b = blockIdx.y;
  const int slice = blockIdx.x;
  const int tid = threadIdx.x;

  // ---- reduce k_sums partials in parallel (8 independent loads/thread) ----
  {
    const int c64 = tid & 63, q = tid >> 6;
    const int t_ = c64 >> 5, c32 = c64 & 31;
    const float* pp = ctrl + CT_PART + (((size_t)t_ * NBATCH + b) * SLICES1) * 32 + c32;
    float s8 = 0.f;
#pragma unroll
    for (int k = 0; k < 8; ++k) s8 += pp[(q * 8 + k) * 32];
    ldp[q][c64] = s8;
  }
  if (tid < 32) ldn[tid] = ctrl[CT_N1P + b * SLICES1 + tid];
  __syncthreads();

  if (tid < 64) {
    float n1 = 0.f;
#pragma unroll
    for (int k = 0; k < 32; ++k) n1 += ldn[k];
    const int cls = (tid >> 4) & 1;
    const float cnt = (cls ? n1 : ((float)HW - n1)) + 1e-6f;
    sm[tid] = (ldp[0][tid] + ldp[1][tid] + ldp[2][tid] + ldp[3][tid]) / cnt;
  }
  __syncthreads();
  if (tid < 4) {  // tid = t*2+cls
    float ss = 0.f;
    const int base_ = (tid >> 1) * 32 + (tid & 1) * 16;
#pragma unroll
    for (int c = 0; c < NCH; ++c) { const float v = sm[base_ + c]; ss = fmaf(v, v, ss); }
    sm[64 + tid] = sqrtf(ss);
  }
  __syncthreads();

  const int* tb = tgt + (size_t)b * HW;
  float lacc = 0.f;

  if constexpr (CACHE) {
    const _Float16* cS = cache + (size_t)b * NCH * HW;
    const _Float16* cT = cache + ((size_t)(NBATCH + b)) * NCH * HW;
    const float rS0 = 1.f / fmaxf(sm[64], 1e-8f);
    const float rS1 = 1.f / fmaxf(sm[65], 1e-8f);
    const float rT0 = 1.f / fmaxf(sm[66], 1e-8f);
    const float rT1 = 1.f / fmaxf(sm[67], 1e-8f);

    const int p = slice * (HW / SLICES2) + tid * 8;  // 8 px, one shot
    const int4 tva = *(const int4*)(tb + p);
    const int4 tvb = *(const int4*)(tb + p + 4);
    const int t8[8] = {tva.x, tva.y, tva.z, tva.w, tvb.x, tvb.y, tvb.z, tvb.w};

    h8 xs[NCH], xt[NCH];
#pragma unroll
    for (int i = 0; i < NCH; ++i)
      xs[i] = __builtin_nontemporal_load((const h8*)(cS + (size_t)i * HW + p));
#pragma unroll
    for (int i = 0; i < NCH; ++i)
      xt[i] = __builtin_nontemporal_load((const h8*)(cT + (size_t)i * HW + p));

    // ---- S (T loads still in flight; xs freed after this block) ----
    float a0[8], a1[8];
#pragma unroll
    for (int k = 0; k < 8; ++k) { a0[k] = 0.f; a1[k] = 0.f; }
#pragma unroll
    for (int i = 0; i < NCH; ++i) {
      const float w0 = sm[i], w1 = sm[16 + i];
#pragma unroll
      for (int k = 0; k < 8; ++k) {
        const float xv = (float)xs[i][k];
        a0[k] = fmaf(xv, w0, a0[k]);
        a1[k] = fmaf(xv, w1, a1[k]);
      }
    }
    float pcS[8];
#pragma unroll
    for (int k = 0; k < 8; ++k)
      pcS[k] = expf((t8[k] == 1) ? a1[k] * rS1 - a0[k] * rS0
                                 : a0[k] * rS0 - a1[k] * rS1);

    // ---- T ----
#pragma unroll
    for (int k = 0; k < 8; ++k) { a0[k] = 0.f; a1[k] = 0.f; }
#pragma unroll
    for (int i = 0; i < NCH; ++i) {
      const float w0 = sm[32 + i], w1 = sm[48 + i];
#pragma unroll
      for (int k = 0; k < 8; ++k) {
        const float xv = (float)xt[i][k];
        a0[k] = fmaf(xv, w0, a0[k]);
        a1[k] = fmaf(xv, w1, a1[k]);
      }
    }
#pragma unroll
    for (int k = 0; k < 8; ++k) {
      const float pcT = expf((t8[k] == 1) ? a1[k] * rT1 - a0[k] * rT0
                                          : a0[k] * rT0 - a1[k] * rT1);
      const float e = pcS[k] - pcT;
      lacc = fmaf(e, e, lacc);
    }
  } else {
    const float* Sb = S + (size_t)b * NCH * HW;
    const float* Tb = T + (size_t)b * NCH * HW;
    const float nmS0 = sm[64], nmS1 = sm[65], nmT0 = sm[66], nmT1 = sm[67];
    const int base = slice * (HW / SLICES2) + tid * 2;  // + it*(TPB*2)

    for (int it = 0; it < 4; ++it) {
      const int p = base + it * (TPB * 2);
      const int2 tv = *(const int2*)(tb + p);
      float2 xs[NCH], xt[NCH];
#pragma unroll
      for (int i = 0; i < NCH; ++i) xs[i] = *(const float2*)(Sb + (size_t)i * HW + p);
#pragma unroll
      for (int i = 0; i < NCH; ++i) xt[i] = *(const float2*)(Tb + (size_t)i * HW + p);

      float ss0 = 0.f, ss1 = 0.f, d00 = 0.f, d01 = 0.f, d10 = 0.f, d11 = 0.f;
#pragma unroll
      for (int i = 0; i < NCH; ++i) {
        const float w0 = sm[i], w1 = sm[16 + i];
        ss0 = fmaf(xs[i].x, xs[i].x, ss0); ss1 = fmaf(xs[i].y, xs[i].y, ss1);
        d00 = fmaf(xs[i].x, w0, d00);      d01 = fmaf(xs[i].y, w0, d01);
        d10 = fmaf(xs[i].x, w1, d10);      d11 = fmaf(xs[i].y, w1, d11);
      }
      const float pcS0 = pc_one(ss0, d00, d10, tv.x, nmS0, nmS1);
      const float pcS1 = pc_one(ss1, d01, d11, tv.y, nmS0, nmS1);

      ss0 = 0.f; ss1 = 0.f; d00 = 0.f; d01 = 0.f; d10 = 0.f; d11 = 0.f;
#pragma unroll
      for (int i = 0; i < NCH; ++i) {
        const float w0 = sm[32 + i], w1 = sm[48 + i];
        ss0 = fmaf(xt[i].x, xt[i].x, ss0); ss1 = fmaf(xt[i].y, xt[i].y, ss1);
        d00 = fmaf(xt[i].x, w0, d00);      d01 = fmaf(xt[i].y, w0, d01);
        d10 = fmaf(xt[i].x, w1, d10);      d11 = fmaf(xt[i].y, w1, d11);
      }
      const float pcT0 = pc_one(ss0, d00, d10, tv.x, nmT0, nmT1);
      const float pcT1 = pc_one(ss1, d01, d11, tv.y, nmT0, nmT1);

      const float e0 = pcS0 - pcT0, e1 = pcS1 - pcT1;
      lacc += e0 * e0 + e1 * e1;
    }
  }

  lacc = wave_sum(lacc);
  if ((tid & 63) == 0) red4[tid >> 6] = lacc;
  __syncthreads();
  if (tid == 0)
    ctrl[CT_LOSSP + b * SLICES2 + slice] = red4[0] + red4[1] + red4[2] + red4[3];
}

// one block: reduce the 1024 disjoint loss partials (no atomics anywhere)
__global__ void k_final(const float* __restrict__ ctrl, float* __restrict__ out) {
  __shared__ float r4[4];
  const int tid = threadIdx.x;
  float s = ctrl[CT_LOSSP + tid] + ctrl[CT_LOSSP + tid + 256] +
            ctrl[CT_LOSSP + tid + 512] + ctrl[CT_LOSSP + tid + 768];
  s = wave_sum(s);
  if ((tid & 63) == 0) r4[tid >> 6] = s;
  __syncthreads();
  if (tid == 0)
    out[0] = (r4[0] + r4[1] + r4[2] + r4[3]) * (1.f / 2097152.f);  // N = 2^21
}

extern "C" void kernel_launch(void* const* d_in, const int* in_sizes, int n_in,
                              void* d_out, int out_size, void* d_ws, size_t ws_size,
                              hipStream_t stream) {
  const float* S = (const float*)d_in[0];
  const float* T = (const float*)d_in[1];
  const int* tgt = (const int*)d_in[2];
  float* out = (float*)d_out;

  const size_t need = CACHE_BYTES + (size_t)CT_FLOATS * 4;
  const bool cached = ws_size >= need;
  _Float16* cache = (_Float16*)d_ws;
  float* ctrl = cached ? (float*)((char*)d_ws + CACHE_BYTES) : (float*)d_ws;

  dim3 g1(SLICES1, NBATCH, 2);
  dim3 g2(SLICES2, NBATCH);
  if (cached) {
    k_sums<true><<<g1, TPB, 0, stream>>>(S, T, tgt, ctrl, cache);
    k_pass2<true><<<g2, TPB, 0, stream>>>(S, T, tgt, ctrl, cache);
  } else {
    k_sums<false><<<g1, TPB, 0, stream>>>(S, T, tgt, ctrl, cache);
    k_pass2<false><<<g2, TPB, 0, stream>>>(S, T, tgt, ctrl, cache);
  }
  k_final<<<1, 256, 0, stream>>>(ctrl, out);
}